// Round 2
// baseline (3250.778 us; speedup 1.0000x reference)
//
#include <hip/hip_runtime.h>

#define HC 256        // HEADS*OUT_CH
#define NEG_SLOPE 0.2f

// ---------------------------------------------------------------------------
// K1: h = x @ W  (M=nnodes, K=256, N=256) fp32, fused a_src/a_dst epilogue.
// Block: 256 threads = 4 waves. Block tile: 32 rows x 256 cols.
// Wave w handles rows [32*bid + 8w, +8); lane handles cols [4*lane, +4).
// x rows staged in LDS (32 KB); W read as float4 (L2-resident, 256 KB).
// ---------------------------------------------------------------------------
__global__ __launch_bounds__(256) void gemm_att(
    const float* __restrict__ x, const float* __restrict__ W,
    const float* __restrict__ att_src, const float* __restrict__ att_dst,
    float* __restrict__ h, float* __restrict__ a_src, float* __restrict__ a_dst,
    int nnodes)
{
  __shared__ float xs[32 * 256];
  const int t    = threadIdx.x;
  const int wave = t >> 6;
  const int lane = t & 63;
  const int row0 = blockIdx.x * 32;

  // stage 32 rows of x (zero-pad past nnodes)
  #pragma unroll
  for (int i = 0; i < 32; ++i) {
    int r = row0 + i;
    xs[i * 256 + t] = (r < nnodes) ? x[(size_t)r * 256 + t] : 0.f;
  }
  __syncthreads();

  float4 acc[8];
  #pragma unroll
  for (int r = 0; r < 8; ++r) acc[r] = make_float4(0.f, 0.f, 0.f, 0.f);

  const int col = lane * 4;
  const float* Wc   = W + col;
  const float* xrow = &xs[(wave * 8) * 256];

  for (int k0 = 0; k0 < 64; ++k0) {
    const float4 w0 = *(const float4*)(Wc + (4 * k0 + 0) * 256);
    const float4 w1 = *(const float4*)(Wc + (4 * k0 + 1) * 256);
    const float4 w2 = *(const float4*)(Wc + (4 * k0 + 2) * 256);
    const float4 w3 = *(const float4*)(Wc + (4 * k0 + 3) * 256);
    #pragma unroll
    for (int r = 0; r < 8; ++r) {
      const float4 xv = *(const float4*)(xrow + r * 256 + 4 * k0);
      acc[r].x += xv.x * w0.x + xv.y * w1.x + xv.z * w2.x + xv.w * w3.x;
      acc[r].y += xv.x * w0.y + xv.y * w1.y + xv.z * w2.y + xv.w * w3.y;
      acc[r].z += xv.x * w0.z + xv.y * w1.z + xv.z * w2.z + xv.w * w3.z;
      acc[r].w += xv.x * w0.w + xv.y * w1.w + xv.z * w2.w + xv.w * w3.w;
    }
  }

  // epilogue: write h, reduce a_src/a_dst per (row, head).
  // lane's 4 cols all belong to head = lane>>4; att flat index = 4*lane.
  const int head = lane >> 4;
  const float4 as4 = ((const float4*)att_src)[lane];
  const float4 ad4 = ((const float4*)att_dst)[lane];

  #pragma unroll
  for (int r = 0; r < 8; ++r) {
    const int row = row0 + wave * 8 + r;
    if (row >= nnodes) break;  // wave-uniform
    *(float4*)&h[(size_t)row * 256 + col] = acc[r];
    float ps = acc[r].x * as4.x + acc[r].y * as4.y + acc[r].z * as4.z + acc[r].w * as4.w;
    float pd = acc[r].x * ad4.x + acc[r].y * ad4.y + acc[r].z * ad4.z + acc[r].w * ad4.w;
    #pragma unroll
    for (int off = 8; off > 0; off >>= 1) {
      ps += __shfl_down(ps, off, 16);
      pd += __shfl_down(pd, off, 16);
    }
    if ((lane & 15) == 0) {
      a_src[row * 4 + head] = ps;
      a_dst[row * 4 + head] = pd;
    }
  }
}

// ---------------------------------------------------------------------------
// K2: per edge: denom[dst][h] += exp(leaky_relu(a_src[src]+a_dst[dst])).
// Self-loops appended logically at e >= E. No segment-max needed: softmax is
// shift-invariant and |alpha| <~ 8, so exp cannot overflow in fp32. The
// 1e-16 denominator epsilon is negligible because every node has a self-loop
// (denom >= exp(alpha_self) > 0).
// ---------------------------------------------------------------------------
__global__ void edge_pass_a(const int* __restrict__ ei,
                            const float* __restrict__ a_src,
                            const float* __restrict__ a_dst,
                            float* __restrict__ denom,
                            int E, int Etot)
{
  const int e = blockIdx.x * blockDim.x + threadIdx.x;
  if (e >= Etot) return;
  int s, d;
  if (e < E) { s = ei[e]; d = ei[E + e]; } else { s = d = e - E; }

  const float4 as = ((const float4*)a_src)[s];
  const float4 ad = ((const float4*)a_dst)[d];
  float4 av;
  av.x = as.x + ad.x; av.y = as.y + ad.y; av.z = as.z + ad.z; av.w = as.w + ad.w;
  av.x = av.x > 0.f ? av.x : NEG_SLOPE * av.x;
  av.y = av.y > 0.f ? av.y : NEG_SLOPE * av.y;
  av.z = av.z > 0.f ? av.z : NEG_SLOPE * av.z;
  av.w = av.w > 0.f ? av.w : NEG_SLOPE * av.w;
  av.x = expf(av.x); av.y = expf(av.y); av.z = expf(av.z); av.w = expf(av.w);

  atomicAdd(&denom[d * 4 + 0], av.x);
  atomicAdd(&denom[d * 4 + 1], av.y);
  atomicAdd(&denom[d * 4 + 2], av.z);
  atomicAdd(&denom[d * 4 + 3], av.w);
}

// ---------------------------------------------------------------------------
// K3: scatter: out[dst] += coef * h[src]. 64 threads per edge, float4 each.
// coef recomputed inline (2 broadcast scalar loads + expf) — this removed the
// 13.6 MB evals buffer that was overflowing d_ws.
// ---------------------------------------------------------------------------
__global__ void scatter_kernel(const int* __restrict__ ei,
                               const float* __restrict__ h,
                               const float* __restrict__ a_src,
                               const float* __restrict__ a_dst,
                               const float* __restrict__ denom,
                               float* __restrict__ out, int E, int Etot)
{
  const long long tid = (long long)blockIdx.x * blockDim.x + threadIdx.x;
  if (tid >= (long long)Etot * 64) return;
  const int e = (int)(tid >> 6);
  const int s = (int)(tid & 63);
  int src, dst;
  if (e < E) { src = ei[e]; dst = ei[E + e]; } else { src = dst = e - E; }
  const int head = s >> 4;

  float alpha = a_src[src * 4 + head] + a_dst[dst * 4 + head];
  alpha = alpha > 0.f ? alpha : NEG_SLOPE * alpha;
  const float c = expf(alpha) / (denom[dst * 4 + head] + 1e-16f);

  const int cb = s * 4;
  const float4 hv = *(const float4*)&h[(size_t)src * 256 + cb];
  float* op = &out[(size_t)dst * 256 + cb];
  atomicAdd(op + 0, c * hv.x);
  atomicAdd(op + 1, c * hv.y);
  atomicAdd(op + 2, c * hv.z);
  atomicAdd(op + 3, c * hv.w);
}

// ---------------------------------------------------------------------------
// K4: out = relu(out + bias), in place.
// ---------------------------------------------------------------------------
__global__ void finalize(float* __restrict__ out, const float* __restrict__ bias, int n)
{
  const int i = blockIdx.x * blockDim.x + threadIdx.x;
  if (i >= n) return;
  const float v = out[i] + bias[i & 255];
  out[i] = v > 0.f ? v : 0.f;
}

extern "C" void kernel_launch(void* const* d_in, const int* in_sizes, int n_in,
                              void* d_out, int out_size, void* d_ws, size_t ws_size,
                              hipStream_t stream)
{
  const float* x       = (const float*)d_in[0];
  const int*   ei      = (const int*)d_in[1];
  const float* W       = (const float*)d_in[2];
  const float* att_src = (const float*)d_in[3];
  const float* att_dst = (const float*)d_in[4];
  const float* bias    = (const float*)d_in[5];

  const int nnodes = in_sizes[0] / HC;   // 50000
  const int E      = in_sizes[1] / 2;    // 800000
  const int Etot   = E + nnodes;         // + self loops

  float* out = (float*)d_out;
  char* ws = (char*)d_ws;
  // Workspace: h (51.2 MB) + a_src/a_dst/denom (0.8 MB each) = 53.6 MB total.
  float* h      = (float*)ws;                                 // nnodes*256
  float* a_src  = (float*)(ws + (size_t)nnodes * HC * 4);     // nnodes*4
  float* a_dst  = a_src + (size_t)nnodes * 4;                 // nnodes*4
  float* denom  = a_dst + (size_t)nnodes * 4;                 // nnodes*4

  hipMemsetAsync(d_out, 0, (size_t)out_size * sizeof(float), stream);
  hipMemsetAsync(denom, 0, (size_t)nnodes * 4 * sizeof(float), stream);

  gemm_att<<<(nnodes + 31) / 32, 256, 0, stream>>>(
      x, W, att_src, att_dst, h, a_src, a_dst, nnodes);

  edge_pass_a<<<(Etot + 255) / 256, 256, 0, stream>>>(
      ei, a_src, a_dst, denom, E, Etot);

  const long long nscatter = (long long)Etot * 64;
  scatter_kernel<<<(int)((nscatter + 255) / 256), 256, 0, stream>>>(
      ei, h, a_src, a_dst, denom, out, E, Etot);

  finalize<<<(out_size + 255) / 256, 256, 0, stream>>>(out, bias, out_size);
}

// Round 3
// 547.527 us; speedup vs baseline: 5.9372x; 5.9372x over previous
//
#include <hip/hip_runtime.h>

#define HC 256        // HEADS*OUT_CH
#define NEG_SLOPE 0.2f

// ---------------------------------------------------------------------------
// K1: h = x @ W  (M=nnodes, K=256, N=256) fp32, fused a_src/a_dst epilogue.
// (unchanged from round 2 — profiles below top-5 so far)
// ---------------------------------------------------------------------------
__global__ __launch_bounds__(256) void gemm_att(
    const float* __restrict__ x, const float* __restrict__ W,
    const float* __restrict__ att_src, const float* __restrict__ att_dst,
    float* __restrict__ h, float* __restrict__ a_src, float* __restrict__ a_dst,
    int nnodes)
{
  __shared__ float xs[32 * 256];
  const int t    = threadIdx.x;
  const int wave = t >> 6;
  const int lane = t & 63;
  const int row0 = blockIdx.x * 32;

  #pragma unroll
  for (int i = 0; i < 32; ++i) {
    int r = row0 + i;
    xs[i * 256 + t] = (r < nnodes) ? x[(size_t)r * 256 + t] : 0.f;
  }
  __syncthreads();

  float4 acc[8];
  #pragma unroll
  for (int r = 0; r < 8; ++r) acc[r] = make_float4(0.f, 0.f, 0.f, 0.f);

  const int col = lane * 4;
  const float* Wc   = W + col;
  const float* xrow = &xs[(wave * 8) * 256];

  for (int k0 = 0; k0 < 64; ++k0) {
    const float4 w0 = *(const float4*)(Wc + (4 * k0 + 0) * 256);
    const float4 w1 = *(const float4*)(Wc + (4 * k0 + 1) * 256);
    const float4 w2 = *(const float4*)(Wc + (4 * k0 + 2) * 256);
    const float4 w3 = *(const float4*)(Wc + (4 * k0 + 3) * 256);
    #pragma unroll
    for (int r = 0; r < 8; ++r) {
      const float4 xv = *(const float4*)(xrow + r * 256 + 4 * k0);
      acc[r].x += xv.x * w0.x + xv.y * w1.x + xv.z * w2.x + xv.w * w3.x;
      acc[r].y += xv.x * w0.y + xv.y * w1.y + xv.z * w2.y + xv.w * w3.y;
      acc[r].z += xv.x * w0.z + xv.y * w1.z + xv.z * w2.z + xv.w * w3.z;
      acc[r].w += xv.x * w0.w + xv.y * w1.w + xv.z * w2.w + xv.w * w3.w;
    }
  }

  const int head = lane >> 4;
  const float4 as4 = ((const float4*)att_src)[lane];
  const float4 ad4 = ((const float4*)att_dst)[lane];

  #pragma unroll
  for (int r = 0; r < 8; ++r) {
    const int row = row0 + wave * 8 + r;
    if (row >= nnodes) break;  // wave-uniform
    *(float4*)&h[(size_t)row * 256 + col] = acc[r];
    float ps = acc[r].x * as4.x + acc[r].y * as4.y + acc[r].z * as4.z + acc[r].w * as4.w;
    float pd = acc[r].x * ad4.x + acc[r].y * ad4.y + acc[r].z * ad4.z + acc[r].w * ad4.w;
    #pragma unroll
    for (int off = 8; off > 0; off >>= 1) {
      ps += __shfl_down(ps, off, 16);
      pd += __shfl_down(pd, off, 16);
    }
    if ((lane & 15) == 0) {
      a_src[row * 4 + head] = ps;
      a_dst[row * 4 + head] = pd;
    }
  }
}

// ---------------------------------------------------------------------------
// CSR build step 1: per-dst degree count (real edges only; self-loops are
// handled explicitly in the gather kernel).
// ---------------------------------------------------------------------------
__global__ void deg_count(const int* __restrict__ ei, int* __restrict__ deg, int E)
{
  const int e = blockIdx.x * blockDim.x + threadIdx.x;
  if (e >= E) return;
  atomicAdd(&deg[ei[E + e]], 1);
}

// ---------------------------------------------------------------------------
// CSR build step 2: exclusive scan of deg -> rowptr (+ cursor copy).
// Single block; thread t owns a contiguous segment. ~2 syncthreads total.
// ---------------------------------------------------------------------------
__global__ __launch_bounds__(256) void scan_csr(const int* __restrict__ deg,
                                                int* __restrict__ rowptr,
                                                int* __restrict__ cursor, int n)
{
  __shared__ int sums[256];
  const int t  = threadIdx.x;
  const int seg = (n + 255) / 256;
  const int lo = min(t * seg, n);
  const int hi = min(lo + seg, n);

  int s = 0;
  for (int i = lo; i < hi; ++i) s += deg[i];
  sums[t] = s;
  __syncthreads();

  if (t == 0) {
    int run = 0;
    for (int i = 0; i < 256; ++i) { int v = sums[i]; sums[i] = run; run += v; }
    rowptr[n] = run;
  }
  __syncthreads();

  int run = sums[t];
  for (int i = lo; i < hi; ++i) {
    rowptr[i] = run;
    cursor[i] = run;
    run += deg[i];
  }
}

// ---------------------------------------------------------------------------
// CSR build step 3: bucket srcs by dst.
// ---------------------------------------------------------------------------
__global__ void fill_csr(const int* __restrict__ ei, int* __restrict__ cursor,
                         int* __restrict__ csr_src, int E)
{
  const int e = blockIdx.x * blockDim.x + threadIdx.x;
  if (e >= E) return;
  const int d = ei[E + e];
  const int pos = atomicAdd(&cursor[d], 1);
  csr_src[pos] = ei[e];
}

// ---------------------------------------------------------------------------
// K3: gather. One wave per dst node, lane owns 4 channels (head = lane>>4).
// out[d] = relu( (Σ_e exp(lrelu(a_src[s_e]+a_dst[d])) * h[s_e]) / Σ_e exp(..)
//               + bias )
// Softmax normalization applied ONCE at the end (commutes out of the sum).
// Unrolled by 2 so the two (csr_src -> h[src]) dependent-load chains overlap.
// ---------------------------------------------------------------------------
__global__ __launch_bounds__(256) void gather_kernel(
    const int* __restrict__ rowptr, const int* __restrict__ csr_src,
    const float* __restrict__ h, const float* __restrict__ a_src,
    const float* __restrict__ a_dst, const float* __restrict__ bias,
    float* __restrict__ out, int n)
{
  const int wave = threadIdx.x >> 6;
  const int lane = threadIdx.x & 63;
  const int d = blockIdx.x * 4 + wave;
  if (d >= n) return;

  const int head = lane >> 4;
  const int cb   = lane * 4;
  const float ad = a_dst[d * 4 + head];

  // self-loop contribution
  float as = a_src[d * 4 + head];
  float alpha = as + ad;
  alpha = alpha > 0.f ? alpha : NEG_SLOPE * alpha;
  float w = expf(alpha);
  float dsum = w;
  float4 hv = *(const float4*)&h[(size_t)d * 256 + cb];
  float4 acc = make_float4(w * hv.x, w * hv.y, w * hv.z, w * hv.w);

  int j   = rowptr[d];
  const int end = rowptr[d + 1];

  for (; j + 1 < end; j += 2) {
    const int s0 = csr_src[j];
    const int s1 = csr_src[j + 1];
    const float as0 = a_src[s0 * 4 + head];
    const float as1 = a_src[s1 * 4 + head];
    const float4 h0 = *(const float4*)&h[(size_t)s0 * 256 + cb];
    const float4 h1 = *(const float4*)&h[(size_t)s1 * 256 + cb];
    float al0 = as0 + ad; al0 = al0 > 0.f ? al0 : NEG_SLOPE * al0;
    float al1 = as1 + ad; al1 = al1 > 0.f ? al1 : NEG_SLOPE * al1;
    const float w0 = expf(al0);
    const float w1 = expf(al1);
    dsum += w0 + w1;
    acc.x += w0 * h0.x + w1 * h1.x;
    acc.y += w0 * h0.y + w1 * h1.y;
    acc.z += w0 * h0.z + w1 * h1.z;
    acc.w += w0 * h0.w + w1 * h1.w;
  }
  if (j < end) {
    const int s0 = csr_src[j];
    const float as0 = a_src[s0 * 4 + head];
    const float4 h0 = *(const float4*)&h[(size_t)s0 * 256 + cb];
    float al0 = as0 + ad; al0 = al0 > 0.f ? al0 : NEG_SLOPE * al0;
    const float w0 = expf(al0);
    dsum += w0;
    acc.x += w0 * h0.x; acc.y += w0 * h0.y;
    acc.z += w0 * h0.z; acc.w += w0 * h0.w;
  }

  const float inv = 1.f / (dsum + 1e-16f);
  const float4 b4 = ((const float4*)bias)[lane];
  float4 o;
  o.x = acc.x * inv + b4.x; o.x = o.x > 0.f ? o.x : 0.f;
  o.y = acc.y * inv + b4.y; o.y = o.y > 0.f ? o.y : 0.f;
  o.z = acc.z * inv + b4.z; o.z = o.z > 0.f ? o.z : 0.f;
  o.w = acc.w * inv + b4.w; o.w = o.w > 0.f ? o.w : 0.f;
  *(float4*)&out[(size_t)d * 256 + cb] = o;
}

extern "C" void kernel_launch(void* const* d_in, const int* in_sizes, int n_in,
                              void* d_out, int out_size, void* d_ws, size_t ws_size,
                              hipStream_t stream)
{
  const float* x       = (const float*)d_in[0];
  const int*   ei      = (const int*)d_in[1];
  const float* W       = (const float*)d_in[2];
  const float* att_src = (const float*)d_in[3];
  const float* att_dst = (const float*)d_in[4];
  const float* bias    = (const float*)d_in[5];

  const int nnodes = in_sizes[0] / HC;   // 50000
  const int E      = in_sizes[1] / 2;    // 800000

  float* out = (float*)d_out;
  char* ws = (char*)d_ws;
  // Workspace layout (≈56.6 MB total; ws is ~64 MB — round-1 overflow at 67.6):
  float* h      = (float*)ws;                                  // nnodes*256 f32
  float* a_src  = (float*)(ws + (size_t)nnodes * HC * 4);      // nnodes*4 f32
  float* a_dst  = a_src + (size_t)nnodes * 4;                  // nnodes*4 f32
  int*   deg    = (int*)(a_dst + (size_t)nnodes * 4);          // nnodes i32
  int*   rowptr = deg + nnodes;                                // nnodes+1 i32
  int*   cursor = rowptr + nnodes + 1;                         // nnodes i32
  int*   csr    = cursor + nnodes;                             // E i32

  hipMemsetAsync(deg, 0, (size_t)nnodes * sizeof(int), stream);

  gemm_att<<<(nnodes + 31) / 32, 256, 0, stream>>>(
      x, W, att_src, att_dst, h, a_src, a_dst, nnodes);

  deg_count<<<(E + 255) / 256, 256, 0, stream>>>(ei, deg, E);
  scan_csr<<<1, 256, 0, stream>>>(deg, rowptr, cursor, nnodes);
  fill_csr<<<(E + 255) / 256, 256, 0, stream>>>(ei, cursor, csr, E);

  gather_kernel<<<(nnodes + 3) / 4, 256, 0, stream>>>(
      rowptr, csr, h, a_src, a_dst, bias, out, nnodes);
}

// Round 4
// 396.219 us; speedup vs baseline: 8.2045x; 1.3819x over previous
//
#include <hip/hip_runtime.h>

#define HC 256        // HEADS*OUT_CH
#define NEG_SLOPE 0.2f
#define BM 64
#define BK 64
#define LDK 72        // padded LDS k-stride (bf16 elems): 144B rows, 16B-aligned

typedef short short8_t __attribute__((ext_vector_type(8)));
typedef float float4_t __attribute__((ext_vector_type(4)));

__device__ __forceinline__ unsigned short f2bf(float f) {
  unsigned u = __float_as_uint(f);
  return (unsigned short)((u + 0x7fffu + ((u >> 16) & 1u)) >> 16);  // RNE
}
__device__ __forceinline__ float bf2f(unsigned short b) {
  return __uint_as_float(((unsigned)b) << 16);
}

// ---------------------------------------------------------------------------
// K0: Wt[n][k] = bf16(W[k][n]).  256x256, tiny.
// ---------------------------------------------------------------------------
__global__ void wt_kernel(const float* __restrict__ W, unsigned short* __restrict__ Wt)
{
  const int k = blockIdx.x;
  const int n = threadIdx.x;
  Wt[n * 256 + k] = f2bf(W[k * 256 + n]);
}

// ---------------------------------------------------------------------------
// K1: h = x @ W via bf16 MFMA, fp32 accumulate. Fused a_src/a_dst epilogue
// (reduced from fp32 accumulators). h stored as bf16.
// Block: 256 thr = 4 waves; tile 64 rows x 256 cols; wave w owns cols
// [64w,64w+64) == head w. BK=64, 4 k-steps, x converted fp32->bf16 in staging.
// MFMA 16x16x32: A[m=lane&15][k=quad*8+j] (arg0), B[n=lane&15][k] (arg1),
// C/D col=lane&15,row=quad*4+reg (m89/m120-verified layouts).
// ---------------------------------------------------------------------------
__global__ __launch_bounds__(256) void gemm_mfma(
    const float* __restrict__ x, const unsigned short* __restrict__ Wt,
    const float* __restrict__ att_src, const float* __restrict__ att_dst,
    unsigned short* __restrict__ h, float* __restrict__ a_src,
    float* __restrict__ a_dst, int nnodes)
{
  __shared__ unsigned short As[BM * LDK];    // 9216 B
  __shared__ unsigned short Bs[256 * LDK];   // 36864 B
  const int t    = threadIdx.x;
  const int wv   = t >> 6;
  const int lane = t & 63;
  const int r0   = blockIdx.x * BM;

  float4_t acc[4][4] = {};   // [mt][nt]

  for (int k0 = 0; k0 < 256; k0 += BK) {
    __syncthreads();
    // stage A: thread t -> row t>>2, k-chunk (t&3)*16 (16 floats -> 16 bf16)
    {
      const int row = t >> 2, kc = (t & 3) * 16;
      const int gr = r0 + row;
      float4 xv[4];
      if (gr < nnodes) {
        const float4* p = (const float4*)(x + (size_t)gr * 256 + k0 + kc);
        xv[0] = p[0]; xv[1] = p[1]; xv[2] = p[2]; xv[3] = p[3];
      } else {
        xv[0] = xv[1] = xv[2] = xv[3] = make_float4(0.f, 0.f, 0.f, 0.f);
      }
      const float* f = (const float*)xv;
      unsigned pk[8];
      #pragma unroll
      for (int i = 0; i < 8; ++i)
        pk[i] = (unsigned)f2bf(f[2 * i]) | ((unsigned)f2bf(f[2 * i + 1]) << 16);
      uint4* d = (uint4*)&As[row * LDK + kc];
      d[0] = make_uint4(pk[0], pk[1], pk[2], pk[3]);
      d[1] = make_uint4(pk[4], pk[5], pk[6], pk[7]);
    }
    // stage B: Wt rows (already bf16): 256 rows x 64 k
    #pragma unroll
    for (int it = 0; it < 4; ++it) {
      const int n = it * 64 + (t >> 2);
      const int kc = (t & 3) * 16;
      const uint4* g = (const uint4*)(Wt + (size_t)n * 256 + k0 + kc);
      uint4 v0 = g[0], v1 = g[1];
      uint4* d = (uint4*)&Bs[n * LDK + kc];
      d[0] = v0; d[1] = v1;
    }
    __syncthreads();

    #pragma unroll
    for (int ks = 0; ks < 2; ++ks) {
      const int ko = ks * 32 + (lane >> 4) * 8;
      short8_t af[4], bfr[4];
      #pragma unroll
      for (int mt = 0; mt < 4; ++mt)
        af[mt] = *(const short8_t*)&As[(16 * mt + (lane & 15)) * LDK + ko];
      #pragma unroll
      for (int nt = 0; nt < 4; ++nt)
        bfr[nt] = *(const short8_t*)&Bs[(64 * wv + 16 * nt + (lane & 15)) * LDK + ko];
      #pragma unroll
      for (int mt = 0; mt < 4; ++mt)
        #pragma unroll
        for (int nt = 0; nt < 4; ++nt)
          acc[mt][nt] = __builtin_amdgcn_mfma_f32_16x16x32_bf16(
              af[mt], bfr[nt], acc[mt][nt], 0, 0, 0);
    }
  }

  // epilogue
  const int q = lane >> 4, l15 = lane & 15;
  float atts[4], attd[4];
  #pragma unroll
  for (int nt = 0; nt < 4; ++nt) {
    atts[nt] = att_src[wv * 64 + 16 * nt + l15];
    attd[nt] = att_dst[wv * 64 + 16 * nt + l15];
  }

  #pragma unroll
  for (int mt = 0; mt < 4; ++mt) {
    #pragma unroll
    for (int reg = 0; reg < 4; ++reg) {
      const int row = r0 + 16 * mt + 4 * q + reg;
      const bool ok = row < nnodes;
      float ps = 0.f, pd = 0.f;
      #pragma unroll
      for (int nt = 0; nt < 4; ++nt) {
        const float v = acc[mt][nt][reg];
        if (ok) h[(size_t)row * 256 + 64 * wv + 16 * nt + l15] = f2bf(v);
        ps += v * atts[nt];
        pd += v * attd[nt];
      }
      #pragma unroll
      for (int off = 8; off; off >>= 1) {
        ps += __shfl_down(ps, off, 16);
        pd += __shfl_down(pd, off, 16);
      }
      if (ok && l15 == 0) {
        a_src[row * 4 + wv] = ps;
        a_dst[row * 4 + wv] = pd;
      }
    }
  }
}

// ---------------------------------------------------------------------------
// CSR build
// ---------------------------------------------------------------------------
__global__ void deg_count(const int* __restrict__ ei, int* __restrict__ deg, int E)
{
  const int e = blockIdx.x * blockDim.x + threadIdx.x;
  if (e >= E) return;
  atomicAdd(&deg[ei[E + e]], 1);
}

__global__ __launch_bounds__(1024) void scan_csr(const int* __restrict__ deg,
                                                 int* __restrict__ rowptr,
                                                 int* __restrict__ cursor, int n)
{
  __shared__ int wsum[16], woff[16];
  const int t = threadIdx.x, lane = t & 63, wv = t >> 6;
  const int seg = (n + 1023) / 1024;
  const int lo = min(t * seg, n), hi = min(lo + seg, n);

  int s = 0;
  for (int i = lo; i < hi; ++i) s += deg[i];

  int sc = s;  // inclusive scan within wave
  #pragma unroll
  for (int off = 1; off < 64; off <<= 1) {
    int v = __shfl_up(sc, off, 64);
    if (lane >= off) sc += v;
  }
  if (lane == 63) wsum[wv] = sc;
  __syncthreads();
  if (t == 0) {
    int run = 0;
    #pragma unroll
    for (int i = 0; i < 16; ++i) { int v = wsum[i]; woff[i] = run; run += v; }
    rowptr[n] = run;
  }
  __syncthreads();

  int run = woff[wv] + sc - s;  // exclusive prefix for this thread
  for (int i = lo; i < hi; ++i) {
    rowptr[i] = run;
    cursor[i] = run;
    run += deg[i];
  }
}

__global__ void fill_csr(const int* __restrict__ ei, int* __restrict__ cursor,
                         int* __restrict__ csr_src, int E)
{
  const int e = blockIdx.x * blockDim.x + threadIdx.x;
  if (e >= E) return;
  const int d = ei[E + e];
  const int pos = atomicAdd(&cursor[d], 1);
  csr_src[pos] = ei[e];
}

// ---------------------------------------------------------------------------
// K3: gather, h in bf16 (halved traffic), unrolled x4.
// One wave per dst; lane owns 4 channels (head = lane>>4).
// ---------------------------------------------------------------------------
__device__ __forceinline__ float4 ld_h(const unsigned short* __restrict__ h,
                                       int row, int cb)
{
  const ushort4 u = *(const ushort4*)&h[(size_t)row * 256 + cb];
  return make_float4(bf2f(u.x), bf2f(u.y), bf2f(u.z), bf2f(u.w));
}

__global__ __launch_bounds__(256) void gather_kernel(
    const int* __restrict__ rowptr, const int* __restrict__ csr_src,
    const unsigned short* __restrict__ h, const float* __restrict__ a_src,
    const float* __restrict__ a_dst, const float* __restrict__ bias,
    float* __restrict__ out, int n)
{
  const int wave = threadIdx.x >> 6;
  const int lane = threadIdx.x & 63;
  const int d = blockIdx.x * 4 + wave;
  if (d >= n) return;

  const int head = lane >> 4;
  const int cb   = lane * 4;
  const float ad = a_dst[d * 4 + head];

  // self-loop
  float alpha = a_src[d * 4 + head] + ad;
  alpha = alpha > 0.f ? alpha : NEG_SLOPE * alpha;
  float w = expf(alpha);
  float dsum = w;
  float4 hv = ld_h(h, d, cb);
  float4 acc = make_float4(w * hv.x, w * hv.y, w * hv.z, w * hv.w);

  int j = rowptr[d];
  const int end = rowptr[d + 1];

  for (; j + 3 < end; j += 4) {
    const int s0 = csr_src[j + 0];
    const int s1 = csr_src[j + 1];
    const int s2 = csr_src[j + 2];
    const int s3 = csr_src[j + 3];
    const float a0 = a_src[s0 * 4 + head];
    const float a1 = a_src[s1 * 4 + head];
    const float a2 = a_src[s2 * 4 + head];
    const float a3 = a_src[s3 * 4 + head];
    const float4 h0 = ld_h(h, s0, cb);
    const float4 h1 = ld_h(h, s1, cb);
    const float4 h2 = ld_h(h, s2, cb);
    const float4 h3 = ld_h(h, s3, cb);
    float l0 = a0 + ad; l0 = l0 > 0.f ? l0 : NEG_SLOPE * l0;
    float l1 = a1 + ad; l1 = l1 > 0.f ? l1 : NEG_SLOPE * l1;
    float l2 = a2 + ad; l2 = l2 > 0.f ? l2 : NEG_SLOPE * l2;
    float l3 = a3 + ad; l3 = l3 > 0.f ? l3 : NEG_SLOPE * l3;
    const float w0 = expf(l0), w1 = expf(l1), w2 = expf(l2), w3 = expf(l3);
    dsum += (w0 + w1) + (w2 + w3);
    acc.x += w0 * h0.x + w1 * h1.x + w2 * h2.x + w3 * h3.x;
    acc.y += w0 * h0.y + w1 * h1.y + w2 * h2.y + w3 * h3.y;
    acc.z += w0 * h0.z + w1 * h1.z + w2 * h2.z + w3 * h3.z;
    acc.w += w0 * h0.w + w1 * h1.w + w2 * h2.w + w3 * h3.w;
  }
  for (; j < end; ++j) {
    const int s0 = csr_src[j];
    const float a0 = a_src[s0 * 4 + head];
    const float4 h0 = ld_h(h, s0, cb);
    float l0 = a0 + ad; l0 = l0 > 0.f ? l0 : NEG_SLOPE * l0;
    const float w0 = expf(l0);
    dsum += w0;
    acc.x += w0 * h0.x; acc.y += w0 * h0.y;
    acc.z += w0 * h0.z; acc.w += w0 * h0.w;
  }

  const float inv = 1.f / (dsum + 1e-16f);
  const float4 b4 = ((const float4*)bias)[lane];
  float4 o;
  o.x = acc.x * inv + b4.x; o.x = o.x > 0.f ? o.x : 0.f;
  o.y = acc.y * inv + b4.y; o.y = o.y > 0.f ? o.y : 0.f;
  o.z = acc.z * inv + b4.z; o.z = o.z > 0.f ? o.z : 0.f;
  o.w = acc.w * inv + b4.w; o.w = o.w > 0.f ? o.w : 0.f;
  *(float4*)&out[(size_t)d * 256 + cb] = o;
}

extern "C" void kernel_launch(void* const* d_in, const int* in_sizes, int n_in,
                              void* d_out, int out_size, void* d_ws, size_t ws_size,
                              hipStream_t stream)
{
  const float* x       = (const float*)d_in[0];
  const int*   ei      = (const int*)d_in[1];
  const float* W       = (const float*)d_in[2];
  const float* att_src = (const float*)d_in[3];
  const float* att_dst = (const float*)d_in[4];
  const float* bias    = (const float*)d_in[5];

  const int nnodes = in_sizes[0] / HC;   // 50000
  const int E      = in_sizes[1] / 2;    // 800000

  float* out = (float*)d_out;
  char* ws = (char*)d_ws;
  // Workspace (~31 MB): h bf16 | a_src | a_dst | Wt bf16 | deg | rowptr | cursor | csr
  unsigned short* h  = (unsigned short*)ws;                        // nnodes*256 bf16
  float* a_src = (float*)(ws + (size_t)nnodes * HC * 2);           // nnodes*4 f32
  float* a_dst = a_src + (size_t)nnodes * 4;
  unsigned short* Wt = (unsigned short*)(a_dst + (size_t)nnodes * 4); // 256*256 bf16
  int* deg    = (int*)((char*)Wt + 256 * 256 * 2);
  int* rowptr = deg + nnodes;
  int* cursor = rowptr + nnodes + 1;
  int* csr    = cursor + nnodes;

  hipMemsetAsync(deg, 0, (size_t)nnodes * sizeof(int), stream);

  wt_kernel<<<256, 256, 0, stream>>>(W, Wt);

  gemm_mfma<<<(nnodes + BM - 1) / BM, 256, 0, stream>>>(
      x, Wt, att_src, att_dst, h, a_src, a_dst, nnodes);

  deg_count<<<(E + 255) / 256, 256, 0, stream>>>(ei, deg, E);
  scan_csr<<<1, 1024, 0, stream>>>(deg, rowptr, cursor, nnodes);
  fill_csr<<<(E + 255) / 256, 256, 0, stream>>>(ei, cursor, csr, E);

  gather_kernel<<<(nnodes + 3) / 4, 256, 0, stream>>>(
      rowptr, csr, h, a_src, a_dst, bias, out, nnodes);
}

// Round 5
// 296.984 us; speedup vs baseline: 10.9460x; 1.3341x over previous
//
#include <hip/hip_runtime.h>

#define HC 256        // HEADS*OUT_CH
#define NEG_SLOPE 0.2f
#define BM 64
#define BK 64
#define LDK 72        // padded LDS k-stride (bf16 elems): 144B rows, 16B-aligned

typedef short short8_t __attribute__((ext_vector_type(8)));
typedef float float4_t __attribute__((ext_vector_type(4)));

__device__ __forceinline__ unsigned short f2bf(float f) {
  unsigned u = __float_as_uint(f);
  return (unsigned short)((u + 0x7fffu + ((u >> 16) & 1u)) >> 16);  // RNE
}
__device__ __forceinline__ float bf2f(unsigned short b) {
  return __uint_as_float(((unsigned)b) << 16);
}

// ---------------------------------------------------------------------------
// K0: Wt[n][k] = bf16(W[k][n]).  256x256, tiny.
// ---------------------------------------------------------------------------
__global__ void wt_kernel(const float* __restrict__ W, unsigned short* __restrict__ Wt)
{
  const int k = blockIdx.x;
  const int n = threadIdx.x;
  Wt[n * 256 + k] = f2bf(W[k * 256 + n]);
}

// ---------------------------------------------------------------------------
// K1: h = x @ W via bf16 MFMA, fp32 accumulate. Fused a_src/a_dst epilogue.
// (unchanged from round 4)
// ---------------------------------------------------------------------------
__global__ __launch_bounds__(256) void gemm_mfma(
    const float* __restrict__ x, const unsigned short* __restrict__ Wt,
    const float* __restrict__ att_src, const float* __restrict__ att_dst,
    unsigned short* __restrict__ h, float* __restrict__ a_src,
    float* __restrict__ a_dst, int nnodes)
{
  __shared__ unsigned short As[BM * LDK];    // 9216 B
  __shared__ unsigned short Bs[256 * LDK];   // 36864 B
  const int t    = threadIdx.x;
  const int wv   = t >> 6;
  const int lane = t & 63;
  const int r0   = blockIdx.x * BM;

  float4_t acc[4][4] = {};   // [mt][nt]

  for (int k0 = 0; k0 < 256; k0 += BK) {
    __syncthreads();
    {
      const int row = t >> 2, kc = (t & 3) * 16;
      const int gr = r0 + row;
      float4 xv[4];
      if (gr < nnodes) {
        const float4* p = (const float4*)(x + (size_t)gr * 256 + k0 + kc);
        xv[0] = p[0]; xv[1] = p[1]; xv[2] = p[2]; xv[3] = p[3];
      } else {
        xv[0] = xv[1] = xv[2] = xv[3] = make_float4(0.f, 0.f, 0.f, 0.f);
      }
      const float* f = (const float*)xv;
      unsigned pk[8];
      #pragma unroll
      for (int i = 0; i < 8; ++i)
        pk[i] = (unsigned)f2bf(f[2 * i]) | ((unsigned)f2bf(f[2 * i + 1]) << 16);
      uint4* d = (uint4*)&As[row * LDK + kc];
      d[0] = make_uint4(pk[0], pk[1], pk[2], pk[3]);
      d[1] = make_uint4(pk[4], pk[5], pk[6], pk[7]);
    }
    #pragma unroll
    for (int it = 0; it < 4; ++it) {
      const int n = it * 64 + (t >> 2);
      const int kc = (t & 3) * 16;
      const uint4* g = (const uint4*)(Wt + (size_t)n * 256 + k0 + kc);
      uint4 v0 = g[0], v1 = g[1];
      uint4* d = (uint4*)&Bs[n * LDK + kc];
      d[0] = v0; d[1] = v1;
    }
    __syncthreads();

    #pragma unroll
    for (int ks = 0; ks < 2; ++ks) {
      const int ko = ks * 32 + (lane >> 4) * 8;
      short8_t af[4], bfr[4];
      #pragma unroll
      for (int mt = 0; mt < 4; ++mt)
        af[mt] = *(const short8_t*)&As[(16 * mt + (lane & 15)) * LDK + ko];
      #pragma unroll
      for (int nt = 0; nt < 4; ++nt)
        bfr[nt] = *(const short8_t*)&Bs[(64 * wv + 16 * nt + (lane & 15)) * LDK + ko];
      #pragma unroll
      for (int mt = 0; mt < 4; ++mt)
        #pragma unroll
        for (int nt = 0; nt < 4; ++nt)
          acc[mt][nt] = __builtin_amdgcn_mfma_f32_16x16x32_bf16(
              af[mt], bfr[nt], acc[mt][nt], 0, 0, 0);
    }
  }

  const int q = lane >> 4, l15 = lane & 15;
  float atts[4], attd[4];
  #pragma unroll
  for (int nt = 0; nt < 4; ++nt) {
    atts[nt] = att_src[wv * 64 + 16 * nt + l15];
    attd[nt] = att_dst[wv * 64 + 16 * nt + l15];
  }

  #pragma unroll
  for (int mt = 0; mt < 4; ++mt) {
    #pragma unroll
    for (int reg = 0; reg < 4; ++reg) {
      const int row = r0 + 16 * mt + 4 * q + reg;
      const bool ok = row < nnodes;
      float ps = 0.f, pd = 0.f;
      #pragma unroll
      for (int nt = 0; nt < 4; ++nt) {
        const float v = acc[mt][nt][reg];
        if (ok) h[(size_t)row * 256 + 64 * wv + 16 * nt + l15] = f2bf(v);
        ps += v * atts[nt];
        pd += v * attd[nt];
      }
      #pragma unroll
      for (int off = 8; off; off >>= 1) {
        ps += __shfl_down(ps, off, 16);
        pd += __shfl_down(pd, off, 16);
      }
      if (ok && l15 == 0) {
        a_src[row * 4 + wv] = ps;
        a_dst[row * 4 + wv] = pd;
      }
    }
  }
}

// ---------------------------------------------------------------------------
// CSR build: degree count, then 3-phase hierarchical exclusive scan
// (round-4 single-block scan was 112 us at 0.14% occupancy — one CU,
// uncoalesced segments; this version is grid-parallel + int4-coalesced).
// ---------------------------------------------------------------------------
__global__ void deg_count(const int* __restrict__ ei, int* __restrict__ deg, int E)
{
  const int e = blockIdx.x * blockDim.x + threadIdx.x;
  if (e >= E) return;
  atomicAdd(&deg[ei[E + e]], 1);
}

// phase 1: block b reduces deg[b*1024 .. b*1024+1023] -> bsum[b]
__global__ __launch_bounds__(256) void scan_p1(const int* __restrict__ deg,
                                               int* __restrict__ bsum, int n)
{
  __shared__ int ws[4];
  const int t = threadIdx.x, lane = t & 63, wv = t >> 6;
  const int base = blockIdx.x * 1024 + t * 4;
  int4 v = make_int4(0, 0, 0, 0);
  if (base + 3 < n) v = *(const int4*)&deg[base];
  else {
    if (base + 0 < n) v.x = deg[base + 0];
    if (base + 1 < n) v.y = deg[base + 1];
    if (base + 2 < n) v.z = deg[base + 2];
  }
  int s = (v.x + v.y) + (v.z + v.w);
  #pragma unroll
  for (int off = 32; off; off >>= 1) s += __shfl_down(s, off, 64);
  if (lane == 0) ws[wv] = s;
  __syncthreads();
  if (t == 0) bsum[blockIdx.x] = (ws[0] + ws[1]) + (ws[2] + ws[3]);
}

// phase 2: single block scans nb block sums (nb <= 1024) -> boff (exclusive),
// writes rowptr[n] = total.
__global__ __launch_bounds__(1024) void scan_p2(const int* __restrict__ bsum,
                                                int* __restrict__ boff,
                                                int* __restrict__ rowptr,
                                                int nb, int n)
{
  __shared__ int wsum[16], woff[16];
  const int t = threadIdx.x, lane = t & 63, wv = t >> 6;
  int v = (t < nb) ? bsum[t] : 0;
  int sc = v;
  #pragma unroll
  for (int off = 1; off < 64; off <<= 1) {
    int u = __shfl_up(sc, off, 64);
    if (lane >= off) sc += u;
  }
  if (lane == 63) wsum[wv] = sc;
  __syncthreads();
  if (t == 0) {
    int run = 0;
    #pragma unroll
    for (int i = 0; i < 16; ++i) { int x = wsum[i]; woff[i] = run; run += x; }
    rowptr[n] = run;
  }
  __syncthreads();
  if (t < nb) boff[t] = woff[wv] + sc - v;
}

// phase 3: block b rescans its 1024 elems, adds boff[b], writes rowptr+cursor.
__global__ __launch_bounds__(256) void scan_p3(const int* __restrict__ deg,
                                               const int* __restrict__ boff,
                                               int* __restrict__ rowptr,
                                               int* __restrict__ cursor, int n)
{
  __shared__ int wsum[4], woff[4];
  const int t = threadIdx.x, lane = t & 63, wv = t >> 6;
  const int base = blockIdx.x * 1024 + t * 4;
  int4 v = make_int4(0, 0, 0, 0);
  if (base + 3 < n) v = *(const int4*)&deg[base];
  else {
    if (base + 0 < n) v.x = deg[base + 0];
    if (base + 1 < n) v.y = deg[base + 1];
    if (base + 2 < n) v.z = deg[base + 2];
  }
  const int s = (v.x + v.y) + (v.z + v.w);
  int sc = s;
  #pragma unroll
  for (int off = 1; off < 64; off <<= 1) {
    int u = __shfl_up(sc, off, 64);
    if (lane >= off) sc += u;
  }
  if (lane == 63) wsum[wv] = sc;
  __syncthreads();
  if (t == 0) {
    int run = 0;
    #pragma unroll
    for (int i = 0; i < 4; ++i) { int x = wsum[i]; woff[i] = run; run += x; }
  }
  __syncthreads();
  int excl = boff[blockIdx.x] + woff[wv] + (sc - s);
  int4 r;
  r.x = excl;
  r.y = r.x + v.x;
  r.z = r.y + v.y;
  r.w = r.z + v.z;
  if (base + 3 < n) {
    *(int4*)&rowptr[base] = r;
    *(int4*)&cursor[base] = r;
  } else {
    if (base + 0 < n) { rowptr[base + 0] = r.x; cursor[base + 0] = r.x; }
    if (base + 1 < n) { rowptr[base + 1] = r.y; cursor[base + 1] = r.y; }
    if (base + 2 < n) { rowptr[base + 2] = r.z; cursor[base + 2] = r.z; }
  }
}

__global__ void fill_csr(const int* __restrict__ ei, int* __restrict__ cursor,
                         int* __restrict__ csr_src, int E)
{
  const int e = blockIdx.x * blockDim.x + threadIdx.x;
  if (e >= E) return;
  const int d = ei[E + e];
  const int pos = atomicAdd(&cursor[d], 1);
  csr_src[pos] = ei[e];
}

// ---------------------------------------------------------------------------
// K3: gather, h in bf16, unrolled x4. (unchanged from round 4)
// ---------------------------------------------------------------------------
__device__ __forceinline__ float4 ld_h(const unsigned short* __restrict__ h,
                                       int row, int cb)
{
  const ushort4 u = *(const ushort4*)&h[(size_t)row * 256 + cb];
  return make_float4(bf2f(u.x), bf2f(u.y), bf2f(u.z), bf2f(u.w));
}

__global__ __launch_bounds__(256) void gather_kernel(
    const int* __restrict__ rowptr, const int* __restrict__ csr_src,
    const unsigned short* __restrict__ h, const float* __restrict__ a_src,
    const float* __restrict__ a_dst, const float* __restrict__ bias,
    float* __restrict__ out, int n)
{
  const int wave = threadIdx.x >> 6;
  const int lane = threadIdx.x & 63;
  const int d = blockIdx.x * 4 + wave;
  if (d >= n) return;

  const int head = lane >> 4;
  const int cb   = lane * 4;
  const float ad = a_dst[d * 4 + head];

  float alpha = a_src[d * 4 + head] + ad;
  alpha = alpha > 0.f ? alpha : NEG_SLOPE * alpha;
  float w = expf(alpha);
  float dsum = w;
  float4 hv = ld_h(h, d, cb);
  float4 acc = make_float4(w * hv.x, w * hv.y, w * hv.z, w * hv.w);

  int j = rowptr[d];
  const int end = rowptr[d + 1];

  for (; j + 3 < end; j += 4) {
    const int s0 = csr_src[j + 0];
    const int s1 = csr_src[j + 1];
    const int s2 = csr_src[j + 2];
    const int s3 = csr_src[j + 3];
    const float a0 = a_src[s0 * 4 + head];
    const float a1 = a_src[s1 * 4 + head];
    const float a2 = a_src[s2 * 4 + head];
    const float a3 = a_src[s3 * 4 + head];
    const float4 h0 = ld_h(h, s0, cb);
    const float4 h1 = ld_h(h, s1, cb);
    const float4 h2 = ld_h(h, s2, cb);
    const float4 h3 = ld_h(h, s3, cb);
    float l0 = a0 + ad; l0 = l0 > 0.f ? l0 : NEG_SLOPE * l0;
    float l1 = a1 + ad; l1 = l1 > 0.f ? l1 : NEG_SLOPE * l1;
    float l2 = a2 + ad; l2 = l2 > 0.f ? l2 : NEG_SLOPE * l2;
    float l3 = a3 + ad; l3 = l3 > 0.f ? l3 : NEG_SLOPE * l3;
    const float w0 = expf(l0), w1 = expf(l1), w2 = expf(l2), w3 = expf(l3);
    dsum += (w0 + w1) + (w2 + w3);
    acc.x += w0 * h0.x + w1 * h1.x + w2 * h2.x + w3 * h3.x;
    acc.y += w0 * h0.y + w1 * h1.y + w2 * h2.y + w3 * h3.y;
    acc.z += w0 * h0.z + w1 * h1.z + w2 * h2.z + w3 * h3.z;
    acc.w += w0 * h0.w + w1 * h1.w + w2 * h2.w + w3 * h3.w;
  }
  for (; j < end; ++j) {
    const int s0 = csr_src[j];
    const float a0 = a_src[s0 * 4 + head];
    const float4 h0 = ld_h(h, s0, cb);
    float l0 = a0 + ad; l0 = l0 > 0.f ? l0 : NEG_SLOPE * l0;
    const float w0 = expf(l0);
    dsum += w0;
    acc.x += w0 * h0.x; acc.y += w0 * h0.y;
    acc.z += w0 * h0.z; acc.w += w0 * h0.w;
  }

  const float inv = 1.f / (dsum + 1e-16f);
  const float4 b4 = ((const float4*)bias)[lane];
  float4 o;
  o.x = acc.x * inv + b4.x; o.x = o.x > 0.f ? o.x : 0.f;
  o.y = acc.y * inv + b4.y; o.y = o.y > 0.f ? o.y : 0.f;
  o.z = acc.z * inv + b4.z; o.z = o.z > 0.f ? o.z : 0.f;
  o.w = acc.w * inv + b4.w; o.w = o.w > 0.f ? o.w : 0.f;
  *(float4*)&out[(size_t)d * 256 + cb] = o;
}

extern "C" void kernel_launch(void* const* d_in, const int* in_sizes, int n_in,
                              void* d_out, int out_size, void* d_ws, size_t ws_size,
                              hipStream_t stream)
{
  const float* x       = (const float*)d_in[0];
  const int*   ei      = (const int*)d_in[1];
  const float* W       = (const float*)d_in[2];
  const float* att_src = (const float*)d_in[3];
  const float* att_dst = (const float*)d_in[4];
  const float* bias    = (const float*)d_in[5];

  const int nnodes = in_sizes[0] / HC;   // 50000
  const int E      = in_sizes[1] / 2;    // 800000
  const int nb     = (nnodes + 1023) / 1024;   // scan blocks (49)

  float* out = (float*)d_out;
  char* ws = (char*)d_ws;
  // Workspace (~31 MB), all segments 16B-aligned:
  unsigned short* h  = (unsigned short*)ws;                          // nnodes*256 bf16
  float* a_src = (float*)(ws + (size_t)nnodes * HC * 2);             // nnodes*4 f32
  float* a_dst = a_src + (size_t)nnodes * 4;
  unsigned short* Wt = (unsigned short*)(a_dst + (size_t)nnodes * 4); // 256*256 bf16
  int* deg    = (int*)((char*)Wt + 256 * 256 * 2);                   // nnodes
  int* rowptr = deg + nnodes;                                        // nnodes+1 (pad to x4)
  int* cursor = rowptr + ((nnodes + 1 + 3) & ~3);                    // nnodes
  int* bsum   = cursor + nnodes;                                     // nb
  int* boff   = bsum + ((nb + 3) & ~3);                              // nb
  int* csr    = boff + ((nb + 3) & ~3);                              // E

  hipMemsetAsync(deg, 0, (size_t)nnodes * sizeof(int), stream);

  wt_kernel<<<256, 256, 0, stream>>>(W, Wt);

  gemm_mfma<<<(nnodes + BM - 1) / BM, 256, 0, stream>>>(
      x, Wt, att_src, att_dst, h, a_src, a_dst, nnodes);

  deg_count<<<(E + 255) / 256, 256, 0, stream>>>(ei, deg, E);
  scan_p1<<<nb, 256, 0, stream>>>(deg, bsum, nnodes);
  scan_p2<<<1, 1024, 0, stream>>>(bsum, boff, rowptr, nb, nnodes);
  scan_p3<<<nb, 256, 0, stream>>>(deg, boff, rowptr, cursor, nnodes);
  fill_csr<<<(E + 255) / 256, 256, 0, stream>>>(ei, cursor, csr, E);

  gather_kernel<<<(nnodes + 3) / 4, 256, 0, stream>>>(
      rowptr, csr, h, a_src, a_dst, bias, out, nnodes);
}

// Round 6
// 276.695 us; speedup vs baseline: 11.7486x; 1.0733x over previous
//
#include <hip/hip_runtime.h>
#include <hip/hip_bf16.h>

#define HC 256        // HEADS*OUT_CH
#define NEG_SLOPE 0.2f
#define BM 64
#define BK 64
#define LDK 72        // padded LDS k-stride (bf16 elems): 144B rows, 16B-aligned

typedef short short8_t __attribute__((ext_vector_type(8)));
typedef float float4_t __attribute__((ext_vector_type(4)));

__device__ __forceinline__ unsigned short f2bf(float f) {
  unsigned u = __float_as_uint(f);
  return (unsigned short)((u + 0x7fffu + ((u >> 16) & 1u)) >> 16);  // RNE
}
__device__ __forceinline__ float bf2f(unsigned short b) {
  return __uint_as_float(((unsigned)b) << 16);
}

// ---------------------------------------------------------------------------
// K0: Wt[n][k] = bf16(W[k][n]).  256x256, tiny.
// ---------------------------------------------------------------------------
__global__ void wt_kernel(const float* __restrict__ W, unsigned short* __restrict__ Wt)
{
  const int k = blockIdx.x;
  const int n = threadIdx.x;
  Wt[n * 256 + k] = f2bf(W[k * 256 + n]);
}

// ---------------------------------------------------------------------------
// K1: h = x @ W via bf16 MFMA. A-staging now uses the HW packed convert
// (v_cvt_pk_bf16_f32 via __float22bfloat162_rn): ~10 VALU/thread/k-step
// instead of ~80 with manual RNE.
// ---------------------------------------------------------------------------
__global__ __launch_bounds__(256) void gemm_mfma(
    const float* __restrict__ x, const unsigned short* __restrict__ Wt,
    const float* __restrict__ att_src, const float* __restrict__ att_dst,
    unsigned short* __restrict__ h, float* __restrict__ a_src,
    float* __restrict__ a_dst, int nnodes)
{
  __shared__ unsigned short As[BM * LDK];    // 9216 B
  __shared__ unsigned short Bs[256 * LDK];   // 36864 B
  const int t    = threadIdx.x;
  const int wv   = t >> 6;
  const int lane = t & 63;
  const int r0   = blockIdx.x * BM;

  float4_t acc[4][4] = {};   // [mt][nt]

  for (int k0 = 0; k0 < 256; k0 += BK) {
    __syncthreads();
    {
      const int row = t >> 2, kc = (t & 3) * 16;
      const int gr = r0 + row;
      float4 xv[4];
      if (gr < nnodes) {
        const float4* p = (const float4*)(x + (size_t)gr * 256 + k0 + kc);
        xv[0] = p[0]; xv[1] = p[1]; xv[2] = p[2]; xv[3] = p[3];
      } else {
        xv[0] = xv[1] = xv[2] = xv[3] = make_float4(0.f, 0.f, 0.f, 0.f);
      }
      const float* f = (const float*)xv;
      unsigned pk[8];
      #pragma unroll
      for (int i = 0; i < 8; ++i) {
        __hip_bfloat162 b2 = __float22bfloat162_rn(make_float2(f[2 * i], f[2 * i + 1]));
        pk[i] = *(unsigned*)&b2;
      }
      uint4* d = (uint4*)&As[row * LDK + kc];
      d[0] = make_uint4(pk[0], pk[1], pk[2], pk[3]);
      d[1] = make_uint4(pk[4], pk[5], pk[6], pk[7]);
    }
    #pragma unroll
    for (int it = 0; it < 4; ++it) {
      const int n = it * 64 + (t >> 2);
      const int kc = (t & 3) * 16;
      const uint4* g = (const uint4*)(Wt + (size_t)n * 256 + k0 + kc);
      uint4 v0 = g[0], v1 = g[1];
      uint4* d = (uint4*)&Bs[n * LDK + kc];
      d[0] = v0; d[1] = v1;
    }
    __syncthreads();

    #pragma unroll
    for (int ks = 0; ks < 2; ++ks) {
      const int ko = ks * 32 + (lane >> 4) * 8;
      short8_t af[4], bfr[4];
      #pragma unroll
      for (int mt = 0; mt < 4; ++mt)
        af[mt] = *(const short8_t*)&As[(16 * mt + (lane & 15)) * LDK + ko];
      #pragma unroll
      for (int nt = 0; nt < 4; ++nt)
        bfr[nt] = *(const short8_t*)&Bs[(64 * wv + 16 * nt + (lane & 15)) * LDK + ko];
      #pragma unroll
      for (int mt = 0; mt < 4; ++mt)
        #pragma unroll
        for (int nt = 0; nt < 4; ++nt)
          acc[mt][nt] = __builtin_amdgcn_mfma_f32_16x16x32_bf16(
              af[mt], bfr[nt], acc[mt][nt], 0, 0, 0);
    }
  }

  const int q = lane >> 4, l15 = lane & 15;
  float atts[4], attd[4];
  #pragma unroll
  for (int nt = 0; nt < 4; ++nt) {
    atts[nt] = att_src[wv * 64 + 16 * nt + l15];
    attd[nt] = att_dst[wv * 64 + 16 * nt + l15];
  }

  #pragma unroll
  for (int mt = 0; mt < 4; ++mt) {
    #pragma unroll
    for (int reg = 0; reg < 4; ++reg) {
      const int row = r0 + 16 * mt + 4 * q + reg;
      const bool ok = row < nnodes;
      float ps = 0.f, pd = 0.f;
      #pragma unroll
      for (int nt = 0; nt < 4; ++nt) {
        const float v = acc[mt][nt][reg];
        if (ok) h[(size_t)row * 256 + 64 * wv + 16 * nt + l15] = f2bf(v);
        ps += v * atts[nt];
        pd += v * attd[nt];
      }
      #pragma unroll
      for (int off = 8; off; off >>= 1) {
        ps += __shfl_down(ps, off, 16);
        pd += __shfl_down(pd, off, 16);
      }
      if (ok && l15 == 0) {
        a_src[row * 4 + wv] = ps;
        a_dst[row * 4 + wv] = pd;
      }
    }
  }
}

// ---------------------------------------------------------------------------
// CSR build
// ---------------------------------------------------------------------------
__global__ void deg_count(const int* __restrict__ ei, int* __restrict__ deg, int E)
{
  const int e = blockIdx.x * blockDim.x + threadIdx.x;
  if (e >= E) return;
  atomicAdd(&deg[ei[E + e]], 1);
}

__global__ __launch_bounds__(256) void scan_p1(const int* __restrict__ deg,
                                               int* __restrict__ bsum, int n)
{
  __shared__ int ws[4];
  const int t = threadIdx.x, lane = t & 63, wv = t >> 6;
  const int base = blockIdx.x * 1024 + t * 4;
  int4 v = make_int4(0, 0, 0, 0);
  if (base + 3 < n) v = *(const int4*)&deg[base];
  else {
    if (base + 0 < n) v.x = deg[base + 0];
    if (base + 1 < n) v.y = deg[base + 1];
    if (base + 2 < n) v.z = deg[base + 2];
  }
  int s = (v.x + v.y) + (v.z + v.w);
  #pragma unroll
  for (int off = 32; off; off >>= 1) s += __shfl_down(s, off, 64);
  if (lane == 0) ws[wv] = s;
  __syncthreads();
  if (t == 0) bsum[blockIdx.x] = (ws[0] + ws[1]) + (ws[2] + ws[3]);
}

__global__ __launch_bounds__(1024) void scan_p2(const int* __restrict__ bsum,
                                                int* __restrict__ boff,
                                                int* __restrict__ rowptr,
                                                int nb, int n)
{
  __shared__ int wsum[16], woff[16];
  const int t = threadIdx.x, lane = t & 63, wv = t >> 6;
  int v = (t < nb) ? bsum[t] : 0;
  int sc = v;
  #pragma unroll
  for (int off = 1; off < 64; off <<= 1) {
    int u = __shfl_up(sc, off, 64);
    if (lane >= off) sc += u;
  }
  if (lane == 63) wsum[wv] = sc;
  __syncthreads();
  if (t == 0) {
    int run = 0;
    #pragma unroll
    for (int i = 0; i < 16; ++i) { int x = wsum[i]; woff[i] = run; run += x; }
    rowptr[n] = run;
  }
  __syncthreads();
  if (t < nb) boff[t] = woff[wv] + sc - v;
}

__global__ __launch_bounds__(256) void scan_p3(const int* __restrict__ deg,
                                               const int* __restrict__ boff,
                                               int* __restrict__ rowptr,
                                               int* __restrict__ cursor, int n)
{
  __shared__ int wsum[4], woff[4];
  const int t = threadIdx.x, lane = t & 63, wv = t >> 6;
  const int base = blockIdx.x * 1024 + t * 4;
  int4 v = make_int4(0, 0, 0, 0);
  if (base + 3 < n) v = *(const int4*)&deg[base];
  else {
    if (base + 0 < n) v.x = deg[base + 0];
    if (base + 1 < n) v.y = deg[base + 1];
    if (base + 2 < n) v.z = deg[base + 2];
  }
  const int s = (v.x + v.y) + (v.z + v.w);
  int sc = s;
  #pragma unroll
  for (int off = 1; off < 64; off <<= 1) {
    int u = __shfl_up(sc, off, 64);
    if (lane >= off) sc += u;
  }
  if (lane == 63) wsum[wv] = sc;
  __syncthreads();
  if (t == 0) {
    int run = 0;
    #pragma unroll
    for (int i = 0; i < 4; ++i) { int x = wsum[i]; woff[i] = run; run += x; }
  }
  __syncthreads();
  int excl = boff[blockIdx.x] + woff[wv] + (sc - s);
  int4 r;
  r.x = excl;
  r.y = r.x + v.x;
  r.z = r.y + v.y;
  r.w = r.z + v.z;
  if (base + 3 < n) {
    *(int4*)&rowptr[base] = r;
    *(int4*)&cursor[base] = r;
  } else {
    if (base + 0 < n) { rowptr[base + 0] = r.x; cursor[base + 0] = r.x; }
    if (base + 1 < n) { rowptr[base + 1] = r.y; cursor[base + 1] = r.y; }
    if (base + 2 < n) { rowptr[base + 2] = r.z; cursor[base + 2] = r.z; }
  }
}

// ---------------------------------------------------------------------------
// fill_csr, XCD-grouped: group g = blockIdx&7 handles only dsts in its 1/8
// node range, so the csr/wexp slices it writes are CONTIGUOUS (rowptr is
// monotone) -> full 64B lines accumulate in one XCD's L2 instead of partial
// dirty copies in 8 L2s (round-5: 53 MB writeback for 3.2 MB payload).
// Also fused: per-edge per-head attention weight exp(lrelu(as+ad)) -> wexp,
// so the gather's inner loop loses expf/lrelu/a_src-gather.
// ---------------------------------------------------------------------------
__global__ __launch_bounds__(256) void fill_csr(
    const int* __restrict__ ei, const float* __restrict__ a_src,
    const float* __restrict__ a_dst, int* __restrict__ cursor,
    int* __restrict__ csr_src, float4* __restrict__ wexp, int E, int nnodes)
{
  const int g    = blockIdx.x & 7;
  const int bg   = blockIdx.x >> 3;
  const int nbg  = gridDim.x >> 3;
  const int gsz  = (nnodes + 7) >> 3;
  const int dlo  = g * gsz;
  const int dhi  = min(dlo + gsz, nnodes);

  for (int e = bg * 256 + threadIdx.x; e < E; e += nbg * 256) {
    const int d = ei[E + e];
    if (d < dlo || d >= dhi) continue;
    const int s = ei[e];
    const int pos = atomicAdd(&cursor[d], 1);
    csr_src[pos] = s;
    const float4 as = ((const float4*)a_src)[s];
    const float4 ad = ((const float4*)a_dst)[d];
    float4 al;
    al.x = as.x + ad.x; al.y = as.y + ad.y;
    al.z = as.z + ad.z; al.w = as.w + ad.w;
    al.x = al.x > 0.f ? al.x : NEG_SLOPE * al.x;
    al.y = al.y > 0.f ? al.y : NEG_SLOPE * al.y;
    al.z = al.z > 0.f ? al.z : NEG_SLOPE * al.z;
    al.w = al.w > 0.f ? al.w : NEG_SLOPE * al.w;
    al.x = expf(al.x); al.y = expf(al.y); al.z = expf(al.z); al.w = expf(al.w);
    wexp[pos] = al;
  }
}

// ---------------------------------------------------------------------------
// K3: gather. Inner loop: int4 csr load (wave-broadcast), scalar wexp load
// per edge (broadcast within head), 8B h load, 4 converts + 4 FMA + dsum.
// ---------------------------------------------------------------------------
__device__ __forceinline__ float4 ld_h(const unsigned short* __restrict__ h,
                                       int row, int cb)
{
  const ushort4 u = *(const ushort4*)&h[(size_t)row * 256 + cb];
  return make_float4(bf2f(u.x), bf2f(u.y), bf2f(u.z), bf2f(u.w));
}

__global__ __launch_bounds__(256) void gather_kernel(
    const int* __restrict__ rowptr, const int* __restrict__ csr_src,
    const float* __restrict__ wexp, const unsigned short* __restrict__ h,
    const float* __restrict__ a_src, const float* __restrict__ a_dst,
    const float* __restrict__ bias, float* __restrict__ out, int n)
{
  const int wave = threadIdx.x >> 6;
  const int lane = threadIdx.x & 63;
  const int d = blockIdx.x * 4 + wave;
  if (d >= n) return;

  const int head = lane >> 4;
  const int cb   = lane * 4;

  // self-loop (weight computed inline; not in csr)
  float alpha = a_src[d * 4 + head] + a_dst[d * 4 + head];
  alpha = alpha > 0.f ? alpha : NEG_SLOPE * alpha;
  float w = expf(alpha);
  float dsum = w;
  float4 hv = ld_h(h, d, cb);
  float4 acc = make_float4(w * hv.x, w * hv.y, w * hv.z, w * hv.w);

  int j = rowptr[d];
  const int end = rowptr[d + 1];

  for (; j + 3 < end; j += 4) {
    const int4 s4 = *(const int4*)&csr_src[j];
    const float w0 = wexp[(j + 0) * 4 + head];
    const float w1 = wexp[(j + 1) * 4 + head];
    const float w2 = wexp[(j + 2) * 4 + head];
    const float w3 = wexp[(j + 3) * 4 + head];
    const float4 h0 = ld_h(h, s4.x, cb);
    const float4 h1 = ld_h(h, s4.y, cb);
    const float4 h2 = ld_h(h, s4.z, cb);
    const float4 h3 = ld_h(h, s4.w, cb);
    dsum += (w0 + w1) + (w2 + w3);
    acc.x += w0 * h0.x + w1 * h1.x + w2 * h2.x + w3 * h3.x;
    acc.y += w0 * h0.y + w1 * h1.y + w2 * h2.y + w3 * h3.y;
    acc.z += w0 * h0.z + w1 * h1.z + w2 * h2.z + w3 * h3.z;
    acc.w += w0 * h0.w + w1 * h1.w + w2 * h2.w + w3 * h3.w;
  }
  for (; j < end; ++j) {
    const int s0 = csr_src[j];
    const float w0 = wexp[j * 4 + head];
    const float4 h0 = ld_h(h, s0, cb);
    dsum += w0;
    acc.x += w0 * h0.x; acc.y += w0 * h0.y;
    acc.z += w0 * h0.z; acc.w += w0 * h0.w;
  }

  const float inv = 1.f / (dsum + 1e-16f);
  const float4 b4 = ((const float4*)bias)[lane];
  float4 o;
  o.x = acc.x * inv + b4.x; o.x = o.x > 0.f ? o.x : 0.f;
  o.y = acc.y * inv + b4.y; o.y = o.y > 0.f ? o.y : 0.f;
  o.z = acc.z * inv + b4.z; o.z = o.z > 0.f ? o.z : 0.f;
  o.w = acc.w * inv + b4.w; o.w = o.w > 0.f ? o.w : 0.f;
  *(float4*)&out[(size_t)d * 256 + cb] = o;
}

extern "C" void kernel_launch(void* const* d_in, const int* in_sizes, int n_in,
                              void* d_out, int out_size, void* d_ws, size_t ws_size,
                              hipStream_t stream)
{
  const float* x       = (const float*)d_in[0];
  const int*   ei      = (const int*)d_in[1];
  const float* W       = (const float*)d_in[2];
  const float* att_src = (const float*)d_in[3];
  const float* att_dst = (const float*)d_in[4];
  const float* bias    = (const float*)d_in[5];

  const int nnodes = in_sizes[0] / HC;   // 50000
  const int E      = in_sizes[1] / 2;    // 800000
  const int nb     = (nnodes + 1023) / 1024;   // scan blocks (49)

  float* out = (float*)d_out;
  char* ws = (char*)d_ws;
  // Workspace (~44 MB), all segments 16B-aligned:
  unsigned short* h  = (unsigned short*)ws;                          // nnodes*256 bf16
  float* a_src = (float*)(ws + (size_t)nnodes * HC * 2);             // nnodes*4 f32
  float* a_dst = a_src + (size_t)nnodes * 4;
  unsigned short* Wt = (unsigned short*)(a_dst + (size_t)nnodes * 4); // 256*256 bf16
  int* deg    = (int*)((char*)Wt + 256 * 256 * 2);                   // nnodes
  int* rowptr = deg + nnodes;                                        // nnodes+1 (pad x4)
  int* cursor = rowptr + ((nnodes + 1 + 3) & ~3);                    // nnodes
  int* bsum   = cursor + nnodes;                                     // nb
  int* boff   = bsum + ((nb + 3) & ~3);                              // nb
  float4* wexp = (float4*)(boff + ((nb + 3) & ~3));                  // E float4 (12.8 MB)
  int* csr    = (int*)(wexp + E);                                    // E

  hipMemsetAsync(deg, 0, (size_t)nnodes * sizeof(int), stream);

  wt_kernel<<<256, 256, 0, stream>>>(W, Wt);

  gemm_mfma<<<(nnodes + BM - 1) / BM, 256, 0, stream>>>(
      x, Wt, att_src, att_dst, h, a_src, a_dst, nnodes);

  deg_count<<<(E + 255) / 256, 256, 0, stream>>>(ei, deg, E);
  scan_p1<<<nb, 256, 0, stream>>>(deg, bsum, nnodes);
  scan_p2<<<1, 1024, 0, stream>>>(bsum, boff, rowptr, nb, nnodes);
  scan_p3<<<nb, 256, 0, stream>>>(deg, boff, rowptr, cursor, nnodes);

  fill_csr<<<1024, 256, 0, stream>>>(ei, a_src, a_dst, cursor, csr,
                                     (float4*)wexp, E, nnodes);

  gather_kernel<<<(nnodes + 3) / 4, 256, 0, stream>>>(
      rowptr, csr, (const float*)wexp, h, a_src, a_dst, bias, out, nnodes);
}